// Round 7
// baseline (62.927 us; speedup 1.0000x reference)
//
#include <hip/hip_runtime.h>

// BahdanauAttnDecoderRNN single-step decode, MI355X — 4 stream-ordered kernels.
// Reference dead code: softmax over size-1 axis => attn_weights == 1.0;
// attn_W/attn_b/scores dead; attn_applied = colsum(encoder_outputs).
// Live work ~178 MB f32 reads (Wout 131 MB dominant) => ~28 us HBM roofline.
// Sync lessons: coop grid.sync (R4, 441us) and polling DAG (R5, 486us) destroy
// streaming BW — but a single-shot last-block atomic (no polling) is safe.
//   D1: colsum partials + gh + emb-half gi + attn ones + ctr:=0     (~5 us)
//   D2: gi2 (192 blocks); LAST block computes GRU gates -> h_new    (~5 us)
//       (kills the 80 MB redundant gates traffic R6's D3 paid)
//   D3: pure logits stream: h_new in regs, Wout 131 MB, per-block
//       online softmax partials                                     (~21 us)
//   D4: fixed-order reduce of 2000 partials + in-place log-softmax  (~2 us)

namespace {
constexpr int H = 1024;
constexpr int V = 32000;
constexpr int S = 2048;
constexpr int NTHR = 256;
constexpr int CS_BLKS = 32;             // colsum chunks
constexpr int CS_ROWS = S / CS_BLKS;    // 64 rows per chunk
constexpr int GRU_BLKS = 768;           // 3072 rows / 4 per block
constexpr int D1_BLKS = CS_BLKS + GRU_BLKS + 1;  // 801
constexpr int D2_BLKS = 192;            // 16 gi2 rows each
constexpr int D3_BLKS = 2000;           // 16 logits rows each
constexpr int D4_BLKS = V / NTHR;       // 125
}

__device__ __forceinline__ float wave_sum(float v) {
#pragma unroll
    for (int off = 32; off > 0; off >>= 1) v += __shfl_xor(v, off, 64);
    return v;
}
__device__ __forceinline__ float wave_max(float v) {
#pragma unroll
    for (int off = 32; off > 0; off >>= 1) v = fmaxf(v, __shfl_xor(v, off, 64));
    return v;
}
__device__ __forceinline__ float dot4(float4 a, float4 b) {
    return a.x * b.x + a.y * b.y + a.z * b.z + a.w * b.w;
}

// D1: colsum partials + gh & emb-half of gi + attn ones + D2-counter reset.
__global__ __launch_bounds__(NTHR) void k_front(
    const float* __restrict__ enc, const float* __restrict__ Whh,
    const float* __restrict__ Wih, const float* __restrict__ bih,
    const float* __restrict__ bhh, const float* __restrict__ hin,
    const float* __restrict__ emb, const int* __restrict__ word,
    float* __restrict__ part, float* __restrict__ gi, float* __restrict__ gh,
    float* __restrict__ out, int* __restrict__ ctr) {
    const int b = blockIdx.x, t = threadIdx.x;
    if (b < CS_BLKS) {
        // rows [b*64, b*64+64); thread t owns float4-column t
        const float4* e = (const float4*)enc + (size_t)b * CS_ROWS * (H / 4) + t;
        float4 acc = make_float4(0.f, 0.f, 0.f, 0.f);
#pragma unroll
        for (int r = 0; r < CS_ROWS; ++r) {
            float4 v = e[(size_t)r * (H / 4)];
            acc.x += v.x; acc.y += v.y; acc.z += v.z; acc.w += v.w;
        }
        ((float4*)part)[b * (H / 4) + t] = acc;
    } else if (b < CS_BLKS + GRU_BLKS) {
        const int lane = t & 63, w = t >> 6;
        const int row = (b - CS_BLKS) * 4 + w;  // < 3072
        const float4* wh = (const float4*)Whh + (size_t)row * (H / 4);
        const float4* xh = (const float4*)hin;
        const float4* wi = (const float4*)Wih + (size_t)row * (2 * H / 4);
        const float4* er = (const float4*)emb + (size_t)word[0] * (H / 4);
        float ah = 0.f, ai = 0.f;
#pragma unroll
        for (int it = 0; it < 4; ++it) {
            const int idx = it * 64 + lane;
            float4 a4 = wh[idx], x4 = xh[idx];
            ah += dot4(a4, x4);
            float4 b4 = wi[idx], e4 = er[idx];
            e4.x = fmaxf(e4.x, 0.f); e4.y = fmaxf(e4.y, 0.f);
            e4.z = fmaxf(e4.z, 0.f); e4.w = fmaxf(e4.w, 0.f);
            ai += dot4(b4, e4);
        }
        ah = wave_sum(ah);
        ai = wave_sum(ai);
        if (lane == 0) {
            gh[row] = ah + bhh[row];
            gi[row] = ai + bih[row];  // colsum half lives in gi2
        }
    } else {
        // attn_weights are exactly 1.0 (softmax over size-1 axis)
#pragma unroll
        for (int k = 0; k < S / NTHR; ++k) out[V + H + k * NTHR + t] = 1.0f;
        // reset D2's arrival counter (robust vs ws poison; D2 runs after D1)
        if (t == 0)
            __hip_atomic_store(ctr, 0, __ATOMIC_RELAXED, __HIP_MEMORY_SCOPE_AGENT);
    }
}

// D2: per-block redundant reduce of 32 colsum partials -> relu -> LDS;
// 16 rows of gi2 = Wih[:, H:2H] . rn. LAST block (single-shot atomic, no
// polling) computes the GRU gates -> h_new (ws) + hidden output (d_out).
__global__ __launch_bounds__(NTHR) void k_gi2(
    const float* __restrict__ Wih, const float* __restrict__ part,
    const float* __restrict__ gi, const float* __restrict__ gh,
    const float* __restrict__ hin, float* __restrict__ gi2,
    float* __restrict__ hnew, float* __restrict__ out, int* __restrict__ ctr) {
    __shared__ float4 rn[H / 4];
    __shared__ int winner;
    const int t = threadIdx.x, lane = t & 63, w = t >> 6;
    float4 acc = make_float4(0.f, 0.f, 0.f, 0.f);
#pragma unroll
    for (int c = 0; c < CS_BLKS; ++c) {
        float4 v = ((const float4*)part)[c * (H / 4) + t];
        acc.x += v.x; acc.y += v.y; acc.z += v.z; acc.w += v.w;
    }
    acc.x = fmaxf(acc.x, 0.f); acc.y = fmaxf(acc.y, 0.f);
    acc.z = fmaxf(acc.z, 0.f); acc.w = fmaxf(acc.w, 0.f);
    rn[t] = acc;
    __syncthreads();
#pragma unroll
    for (int i = 0; i < 4; ++i) {
        const int row = blockIdx.x * 16 + w * 4 + i;  // < 3072
        const float4* wr = (const float4*)Wih + (size_t)row * (2 * H / 4) + (H / 4);
        float a = 0.f;
#pragma unroll
        for (int it = 0; it < 4; ++it) {
            const int idx = it * 64 + lane;
            a += dot4(wr[idx], rn[idx]);
        }
        a = wave_sum(a);
        if (lane == 0) gi2[row] = a;
    }
    // single-shot arrival; winner computes gates (others exit immediately)
    __threadfence();
    __syncthreads();
    if (t == 0) {
        const int old = __hip_atomic_fetch_add(ctr, 1, __ATOMIC_ACQ_REL,
                                               __HIP_MEMORY_SCOPE_AGENT);
        winner = (old == D2_BLKS - 1);
    }
    __syncthreads();
    if (!winner) return;
    __threadfence();  // acquire: see all blocks' gi2 stores
#pragma unroll
    for (int q = 0; q < 4; ++q) {
        const int j = q * NTHR + t;
        const float gr = gi[j] + gi2[j] + gh[j];
        const float gz = gi[H + j] + gi2[H + j] + gh[H + j];
        const float r = 1.f / (1.f + expf(-gr));
        const float z = 1.f / (1.f + expf(-gz));
        const float n = tanhf(gi[2 * H + j] + gi2[2 * H + j] + r * gh[2 * H + j]);
        const float hv = (1.f - z) * n + z * hin[j];
        hnew[j] = hv;
        out[V + j] = hv;  // hidden-state output
    }
}

// D3: pure logits stream. h_new in registers (4 KB broadcast, L2/L3),
// 16 Wout rows per block, raw logits to d_out, ONE (m,s) partial per block.
__global__ __launch_bounds__(NTHR) void k_logits(
    const float* __restrict__ Wout, const float* __restrict__ bout,
    const float* __restrict__ hnew, float* __restrict__ out,
    float* __restrict__ partm, float* __restrict__ parts) {
    __shared__ float bm[4], bs[4];
    const int t = threadIdx.x, lane = t & 63, w = t >> 6;
    const float4* hn4 = (const float4*)hnew;
    const float4 x0 = hn4[lane], x1 = hn4[64 + lane];
    const float4 x2 = hn4[128 + lane], x3 = hn4[192 + lane];
    float m = -3.4e38f, ssum = 0.f;
#pragma unroll
    for (int i = 0; i < 4; ++i) {
        const int row = blockIdx.x * 16 + w * 4 + i;  // < 32000
        const float4* wr = (const float4*)Wout + (size_t)row * (H / 4);
        float a = dot4(wr[lane], x0) + dot4(wr[64 + lane], x1) +
                  dot4(wr[128 + lane], x2) + dot4(wr[192 + lane], x3);
        a = wave_sum(a) + bout[row];  // identical on all lanes
        if (lane == 0) out[row] = a;  // raw logit
        const float mn = fmaxf(m, a);
        ssum = ssum * expf(m - mn) + expf(a - mn);
        m = mn;
    }
    if (lane == 0) { bm[w] = m; bs[w] = ssum; }
    __syncthreads();
    if (t == 0) {
        float M = fmaxf(fmaxf(bm[0], bm[1]), fmaxf(bm[2], bm[3]));
        float s = bs[0] * expf(bm[0] - M) + bs[1] * expf(bm[1] - M) +
                  bs[2] * expf(bm[2] - M) + bs[3] * expf(bm[3] - M);
        partm[blockIdx.x] = M;
        parts[blockIdx.x] = s;
    }
}

// D4: redundant fixed-order reduce of 2000 partials + in-place log-softmax.
__global__ __launch_bounds__(NTHR) void k_final(
    const float* __restrict__ partm, const float* __restrict__ parts,
    float* __restrict__ out) {
    __shared__ float ms[4], ss[4];
    const int t = threadIdx.x, lane = t & 63, w = t >> 6;
    float m = -3.4e38f;
    for (int k = t; k < D3_BLKS; k += NTHR) m = fmaxf(m, partm[k]);
    m = wave_max(m);
    if (lane == 0) ms[w] = m;
    __syncthreads();
    const float M = fmaxf(fmaxf(ms[0], ms[1]), fmaxf(ms[2], ms[3]));
    float s = 0.f;
    for (int k = t; k < D3_BLKS; k += NTHR) s += parts[k] * expf(partm[k] - M);
    s = wave_sum(s);
    if (lane == 0) ss[w] = s;
    __syncthreads();
    const float L = logf(ss[0] + ss[1] + ss[2] + ss[3]);
    const int g = blockIdx.x * NTHR + t;  // 125*256 = 32000
    out[g] = out[g] - M - L;
}

extern "C" void kernel_launch(void* const* d_in, const int* in_sizes, int n_in,
                              void* d_out, int out_size, void* d_ws, size_t ws_size,
                              hipStream_t stream) {
    const int*   word = (const int*)d_in[0];
    const float* hin  = (const float*)d_in[1];
    const float* enc  = (const float*)d_in[2];
    const float* emb  = (const float*)d_in[3];
    // d_in[4] attn_W, d_in[5] attn_b: dead (softmax over size-1 axis)
    const float* Wih  = (const float*)d_in[6];
    const float* Whh  = (const float*)d_in[7];
    const float* bih  = (const float*)d_in[8];
    const float* bhh  = (const float*)d_in[9];
    const float* Wout = (const float*)d_in[10];
    const float* bout = (const float*)d_in[11];
    float* out = (float*)d_out;

    int*   ctr = (int*)d_ws;            // [64 ints pad]
    float* ws  = (float*)d_ws + 64;
    float* part  = ws;                  // [32*1024]
    float* gi    = part + CS_BLKS * H;  // [3072]
    float* gi2   = gi + 3 * H;          // [3072]
    float* gh    = gi2 + 3 * H;         // [3072]
    float* hnew  = gh + 3 * H;          // [1024]
    float* partm = hnew + H;            // [2000]
    float* parts = partm + D3_BLKS;     // [2000]

    k_front<<<D1_BLKS, NTHR, 0, stream>>>(enc, Whh, Wih, bih, bhh, hin, emb, word,
                                          part, gi, gh, out, ctr);
    k_gi2<<<D2_BLKS, NTHR, 0, stream>>>(Wih, part, gi, gh, hin, gi2, hnew, out, ctr);
    k_logits<<<D3_BLKS, NTHR, 0, stream>>>(Wout, bout, hnew, out, partm, parts);
    k_final<<<D4_BLKS, NTHR, 0, stream>>>(partm, parts, out);
}